// Round 2
// baseline (40.285 us; speedup 1.0000x reference)
//
#include <hip/hip_runtime.h>
#include <math.h>

#define H_DIM 2048
#define NUM_K 16
#define NUM_V 32
#define DK 128
#define DV 128
#define KSZ 4
#define KEY_DIM 2048
#define VALUE_DIM 4096
#define CONV_DIM 8192

// workspace layout (floats):
// [0, 8192)        mixed_qkv
// [8192, 12288)    z
// [12288, 12320)   b
// [12320, 12352)   a
// [12352, 20544)   conv_out (after silu)
// [20544, 24640)   out (gated normed core)
#define WS_QKV   0
#define WS_Z     8192
#define WS_B     12288
#define WS_A     12320
#define WS_CONV  12352
#define WS_OUT   20544

__device__ __forceinline__ float wave_reduce_sum(float v) {
#pragma unroll
    for (int off = 32; off > 0; off >>= 1) v += __shfl_down(v, off, 64);
    return v;
}

// ---- Kernel 1: all input projections (wave per row, rows of length 2048) ----
__global__ void proj_kernel(const float* __restrict__ h,
                            const float* __restrict__ qkv_w,
                            const float* __restrict__ z_w,
                            const float* __restrict__ b_w,
                            const float* __restrict__ a_w,
                            float* __restrict__ ws) {
    const int R = CONV_DIM + VALUE_DIM + 2 * NUM_V;  // 12352
    int wave = (blockIdx.x * blockDim.x + threadIdx.x) >> 6;
    int lane = threadIdx.x & 63;
    if (wave >= R) return;

    const float* row;
    float* dst;
    if (wave < CONV_DIM) {
        row = qkv_w + (size_t)wave * H_DIM;
        dst = ws + WS_QKV + wave;
    } else if (wave < CONV_DIM + VALUE_DIM) {
        int r = wave - CONV_DIM;
        row = z_w + (size_t)r * H_DIM;
        dst = ws + WS_Z + r;
    } else if (wave < CONV_DIM + VALUE_DIM + NUM_V) {
        int r = wave - CONV_DIM - VALUE_DIM;
        row = b_w + (size_t)r * H_DIM;
        dst = ws + WS_B + r;
    } else {
        int r = wave - CONV_DIM - VALUE_DIM - NUM_V;
        row = a_w + (size_t)r * H_DIM;
        dst = ws + WS_A + r;
    }

    const float4* row4 = (const float4*)row;
    const float4* h4 = (const float4*)h;
    float acc = 0.f;
#pragma unroll
    for (int i = 0; i < H_DIM / 256; ++i) {  // 8 iters
        float4 w4 = row4[lane + 64 * i];
        float4 hv = h4[lane + 64 * i];
        acc += w4.x * hv.x + w4.y * hv.y + w4.z * hv.z + w4.w * hv.w;
    }
    acc = wave_reduce_sum(acc);
    if (lane == 0) *dst = acc;
}

// ---- Kernel 2: causal-conv update + silu; writes new_conv_state output ----
__global__ void conv_kernel_rw(const float* __restrict__ conv_state,
                               const float* __restrict__ conv_w,
                               float* __restrict__ ws,
                               float* __restrict__ new_conv_state) {
    int c = blockIdx.x * blockDim.x + threadIdx.x;
    if (c >= CONV_DIM) return;
    float4 cs = ((const float4*)conv_state)[c];  // conv_state[c][0..3]
    float4 w = ((const float4*)conv_w)[c];
    float mq = ws[WS_QKV + c];
    // new state = [cs.y, cs.z, cs.w, mq]
    float pre = cs.y * w.x + cs.z * w.y + cs.w * w.z + mq * w.w;
    float so = pre / (1.f + expf(-pre));  // silu
    ws[WS_CONV + c] = so;
    float4 ns;
    ns.x = cs.y; ns.y = cs.z; ns.z = cs.w; ns.w = mq;
    ((float4*)new_conv_state)[c] = ns;
}

// ---- Kernel 3: per-head delta-rule state update + RMSNorm + z-gate ----
// 32 blocks (one per value-head), 128 threads (one per DV column)
__global__ void head_kernel(float* __restrict__ ws,
                            const float* __restrict__ rec_in,
                            const float* __restrict__ dt_bias,
                            const float* __restrict__ A_log,
                            const float* __restrict__ norm_w,
                            float* __restrict__ rec_out) {
    __shared__ float k_lds[DK];
    __shared__ float q_lds[DK];
    __shared__ float redk[2], redq[2], redc[2];

    int n = blockIdx.x;      // value head
    int v = threadIdx.x;     // 0..127
    int sh = n >> 1;         // shared q/k head (VPK=2)
    int wid = v >> 6, lane = v & 63;

    const float* conv_out = ws + WS_CONV;
    float qraw = conv_out[sh * DK + v];
    float kraw = conv_out[KEY_DIM + sh * DK + v];
    float vval = conv_out[2 * KEY_DIM + n * DV + v];

    float ks = wave_reduce_sum(kraw * kraw);
    float qs = wave_reduce_sum(qraw * qraw);
    if (lane == 0) { redk[wid] = ks; redq[wid] = qs; }
    __syncthreads();
    float kin = rsqrtf(redk[0] + redk[1] + 1e-6f);
    float qin = rsqrtf(redq[0] + redq[1] + 1e-6f) * 0.08838834764831845f;  // 1/sqrt(128)
    k_lds[v] = kraw * kin;
    q_lds[v] = qraw * qin;

    // per-head scalars (all threads compute identically)
    float bb = ws[WS_B + n];
    float aa = ws[WS_A + n];
    float beta = 1.f / (1.f + expf(-bb));
    float x = aa + dt_bias[n];
    float sp = (x > 20.f) ? x : log1pf(expf(x));
    float gexp = expf(-expf(A_log[n]) * sp);
    __syncthreads();

    const float* rn = rec_in + (size_t)n * DK * DV;
    float* ro = rec_out + (size_t)n * DK * DV;

    // pass 1: kv_mem[v] = sum_k rec[k][v]*gexp*k_[k]
    float kv = 0.f;
#pragma unroll 8
    for (int k = 0; k < DK; ++k) kv += rn[k * DV + v] * k_lds[k];
    kv *= gexp;
    float delta = (vval - kv) * beta;

    // pass 2: rec' = rec*gexp + k_ outer delta ; core[v] = sum_k rec'[k][v]*q_[k]
    float core = 0.f;
#pragma unroll 8
    for (int k = 0; k < DK; ++k) {
        float val = rn[k * DV + v] * gexp + k_lds[k] * delta;
        ro[k * DV + v] = val;
        core += val * q_lds[k];
    }

    float cs = wave_reduce_sum(core * core);
    if (lane == 0) redc[wid] = cs;
    __syncthreads();
    float var = (redc[0] + redc[1]) * (1.f / DV);
    float xn = core * rsqrtf(var + 1e-6f) * norm_w[v];
    float zv = ws[WS_Z + n * DV + v];
    float silz = zv / (1.f + expf(-zv));
    ws[WS_OUT + n * DV + v] = xn * silz;
}

// ---- Kernel 4: output projection (wave per row, rows of length 4096) ----
__global__ void outproj_kernel(const float* __restrict__ ws,
                               const float* __restrict__ out_proj_w,
                               float* __restrict__ hidden_out) {
    int wave = (blockIdx.x * blockDim.x + threadIdx.x) >> 6;
    int lane = threadIdx.x & 63;
    if (wave >= H_DIM) return;
    const float4* row4 = (const float4*)(out_proj_w + (size_t)wave * VALUE_DIM);
    const float4* o4 = (const float4*)(ws + WS_OUT);
    float acc = 0.f;
#pragma unroll
    for (int i = 0; i < VALUE_DIM / 256; ++i) {  // 16 iters
        float4 w4 = row4[lane + 64 * i];
        float4 ov = o4[lane + 64 * i];
        acc += w4.x * ov.x + w4.y * ov.y + w4.z * ov.z + w4.w * ov.w;
    }
    acc = wave_reduce_sum(acc);
    if (lane == 0) hidden_out[wave] = acc;
}

extern "C" void kernel_launch(void* const* d_in, const int* in_sizes, int n_in,
                              void* d_out, int out_size, void* d_ws, size_t ws_size,
                              hipStream_t stream) {
    const float* h          = (const float*)d_in[0];   // (1,1,2048)
    const float* conv_state = (const float*)d_in[1];   // (1,8192,4)
    const float* rec_in     = (const float*)d_in[2];   // (1,32,128,128)
    const float* conv_w     = (const float*)d_in[3];   // (8192,4)
    const float* qkv_w      = (const float*)d_in[4];   // (8192,2048)
    const float* z_w        = (const float*)d_in[5];   // (4096,2048)
    const float* b_w        = (const float*)d_in[6];   // (32,2048)
    const float* a_w        = (const float*)d_in[7];   // (32,2048)
    const float* out_proj_w = (const float*)d_in[8];   // (2048,4096)
    const float* dt_bias    = (const float*)d_in[9];   // (32,)
    const float* A_log      = (const float*)d_in[10];  // (32,)
    const float* norm_w     = (const float*)d_in[11];  // (128,)

    float* out = (float*)d_out;
    float* hidden_out = out;                           // 2048
    float* new_conv   = out + H_DIM;                   // 32768
    float* rec_out    = out + H_DIM + CONV_DIM * KSZ;  // 524288
    float* ws = (float*)d_ws;

    // 1) projections: 12352 rows, 4 waves/block
    proj_kernel<<<3088, 256, 0, stream>>>(h, qkv_w, z_w, b_w, a_w, ws);
    // 2) conv update
    conv_kernel_rw<<<32, 256, 0, stream>>>(conv_state, conv_w, ws, new_conv);
    // 3) per-head state update
    head_kernel<<<32, 128, 0, stream>>>(ws, rec_in, dt_bias, A_log, norm_w, rec_out);
    // 4) output projection
    outproj_kernel<<<512, 256, 0, stream>>>(ws, out_proj_w, hidden_out);
}

// Round 3
// 32.806 us; speedup vs baseline: 1.2280x; 1.2280x over previous
//
#include <hip/hip_runtime.h>
#include <math.h>

#define H_DIM 2048
#define NUM_K 16
#define NUM_V 32
#define DK 128
#define DV 128
#define KSZ 4
#define KEY_DIM 2048
#define VALUE_DIM 4096
#define CONV_DIM 8192

// workspace layout (floats):
// [0, 8192)        mixed_qkv
// [8192, 12288)    z
// [12288, 12320)   b
// [12320, 12352)   a
// [20544, 24640)   out (gated normed core)
#define WS_QKV   0
#define WS_Z     8192
#define WS_B     12288
#define WS_A     12320
#define WS_OUT   20544

__device__ __forceinline__ float wave_reduce_sum(float v) {
#pragma unroll
    for (int off = 32; off > 0; off >>= 1) v += __shfl_down(v, off, 64);
    return v;
}

// ---- Kernel 1: all input projections (wave per row, rows of length 2048) ----
__global__ void proj_kernel(const float* __restrict__ h,
                            const float* __restrict__ qkv_w,
                            const float* __restrict__ z_w,
                            const float* __restrict__ b_w,
                            const float* __restrict__ a_w,
                            float* __restrict__ ws) {
    const int R = CONV_DIM + VALUE_DIM + 2 * NUM_V;  // 12352
    int wave = (blockIdx.x * blockDim.x + threadIdx.x) >> 6;
    int lane = threadIdx.x & 63;
    if (wave >= R) return;

    const float* row;
    float* dst;
    if (wave < CONV_DIM) {
        row = qkv_w + (size_t)wave * H_DIM;
        dst = ws + WS_QKV + wave;
    } else if (wave < CONV_DIM + VALUE_DIM) {
        int r = wave - CONV_DIM;
        row = z_w + (size_t)r * H_DIM;
        dst = ws + WS_Z + r;
    } else if (wave < CONV_DIM + VALUE_DIM + NUM_V) {
        int r = wave - CONV_DIM - VALUE_DIM;
        row = b_w + (size_t)r * H_DIM;
        dst = ws + WS_B + r;
    } else {
        int r = wave - CONV_DIM - VALUE_DIM - NUM_V;
        row = a_w + (size_t)r * H_DIM;
        dst = ws + WS_A + r;
    }

    const float4* row4 = (const float4*)row;
    const float4* h4 = (const float4*)h;
    float acc = 0.f;
#pragma unroll
    for (int i = 0; i < H_DIM / 256; ++i) {  // 8 iters
        float4 w4 = row4[lane + 64 * i];
        float4 hv = h4[lane + 64 * i];
        acc += w4.x * hv.x + w4.y * hv.y + w4.z * hv.z + w4.w * hv.w;
    }
    acc = wave_reduce_sum(acc);
    if (lane == 0) *dst = acc;
}

// ---- Kernel 2 (fused conv + delta-rule + RMSNorm + gate) ----
// 32 blocks (one per value-head) x 512 threads.
// Thread tiling for rec passes: cg = t&31 -> float4 columns [4cg,4cg+4),
//                               ch = t>>5 -> k-rows [8ch, 8ch+8)
__global__ __launch_bounds__(512) void head_kernel(
        const float* __restrict__ conv_state,
        const float* __restrict__ conv_w,
        float* __restrict__ ws,
        const float* __restrict__ rec_in,
        const float* __restrict__ dt_bias,
        const float* __restrict__ A_log,
        const float* __restrict__ norm_w,
        float* __restrict__ new_conv_state,
        float* __restrict__ rec_out) {
    __shared__ float qc[DK];       // normalized q
    __shared__ float kc[DK];       // normalized k
    __shared__ float vc[DV];
    __shared__ float delta_lds[DV];
    __shared__ float part[16][DV];  // 16 k-chunks x 128 cols partials (8KB)
    __shared__ float red[4];

    const int n = blockIdx.x;        // value head
    const int sh = n >> 1;           // shared q/k head (VPK=2)
    const int t = threadIdx.x;
    const int lane = t & 63;

    // ---- fused causal-conv + silu for this head's q/k/v slices ----
    if (t < 384) {
        int slice = t >> 7;          // 0=q, 1=k, 2=v
        int j = t & 127;
        int c;
        if (slice == 0)      c = sh * DK + j;
        else if (slice == 1) c = KEY_DIM + sh * DK + j;
        else                 c = 2 * KEY_DIM + n * DV + j;
        float4 cs = ((const float4*)conv_state)[c];
        float4 w  = ((const float4*)conv_w)[c];
        float mq  = ws[WS_QKV + c];
        float pre = cs.y * w.x + cs.z * w.y + cs.w * w.z + mq * w.w;
        float so  = pre / (1.f + expf(-pre));  // silu
        if (slice == 0)      qc[j] = so;
        else if (slice == 1) kc[j] = so;
        else                 vc[j] = so;
        // new conv state (q/k written identically by both paired blocks)
        float4 ns; ns.x = cs.y; ns.y = cs.z; ns.z = cs.w; ns.w = mq;
        ((float4*)new_conv_state)[c] = ns;
    }
    __syncthreads();

    // ---- l2 norms of q and k (wave 0 -> q, wave 1 -> k) ----
    if (t < 64) {
        float s = qc[t] * qc[t] + qc[t + 64] * qc[t + 64];
        s = wave_reduce_sum(s);
        if (lane == 0) red[0] = s;
    } else if (t < 128) {
        int j = t - 64;
        float s = kc[j] * kc[j] + kc[j + 64] * kc[j + 64];
        s = wave_reduce_sum(s);
        if (lane == 0) red[1] = s;
    }
    __syncthreads();
    {
        float qin = rsqrtf(red[0] + 1e-6f) * 0.08838834764831845f;  // 1/sqrt(128)
        float kin = rsqrtf(red[1] + 1e-6f);
        if (t < 128) {
            qc[t] *= qin;
            kc[t] *= kin;
        }
    }

    // ---- per-head scalars ----
    float bb = ws[WS_B + n];
    float aa = ws[WS_A + n];
    float beta = 1.f / (1.f + expf(-bb));
    float x = aa + dt_bias[n];
    float sp = (x > 20.f) ? x : log1pf(expf(x));
    float gexp = expf(-expf(A_log[n]) * sp);
    __syncthreads();

    const float4* rn4 = (const float4*)(rec_in + (size_t)n * DK * DV);
    float4* ro4 = (float4*)(rec_out + (size_t)n * DK * DV);
    const int cg = t & 31;
    const int ch = t >> 5;

    // ---- pass 1: kv_mem[v] = sum_k rec[k][v] * k_[k]  (then *gexp) ----
    {
        float4 kv = {0.f, 0.f, 0.f, 0.f};
#pragma unroll
        for (int j = 0; j < 8; ++j) {
            int k = ch * 8 + j;
            float4 r = rn4[k * 32 + cg];
            float kk = kc[k];
            kv.x += r.x * kk; kv.y += r.y * kk; kv.z += r.z * kk; kv.w += r.w * kk;
        }
        ((float4*)part[ch])[cg] = kv;
    }
    __syncthreads();
    if (t < DV) {
        float kv = 0.f;
#pragma unroll
        for (int c = 0; c < 16; ++c) kv += part[c][t];
        kv *= gexp;
        delta_lds[t] = (vc[t] - kv) * beta;
    }
    __syncthreads();

    // ---- pass 2: rec' = rec*gexp + k_ (x) delta; core = rec'^T q_ ----
    {
        float4 d4 = ((const float4*)delta_lds)[cg];
        float4 core = {0.f, 0.f, 0.f, 0.f};
#pragma unroll
        for (int j = 0; j < 8; ++j) {
            int k = ch * 8 + j;
            float4 r = rn4[k * 32 + cg];
            float kk = kc[k];
            float4 val;
            val.x = r.x * gexp + kk * d4.x;
            val.y = r.y * gexp + kk * d4.y;
            val.z = r.z * gexp + kk * d4.z;
            val.w = r.w * gexp + kk * d4.w;
            ro4[k * 32 + cg] = val;
            float qq = qc[k];
            core.x += val.x * qq; core.y += val.y * qq;
            core.z += val.z * qq; core.w += val.w * qq;
        }
        ((float4*)part[ch])[cg] = core;
    }
    __syncthreads();

    // ---- RMSNorm + z-gate ----
    if (t < DV) {
        float core = 0.f;
#pragma unroll
        for (int c = 0; c < 16; ++c) core += part[c][t];
        float s = wave_reduce_sum(core * core);
        if (lane == 0) red[2 + (t >> 6)] = s;
        // stash core in vc (done with v values)
        vc[t] = core;
    }
    __syncthreads();
    if (t < DV) {
        float core = vc[t];
        float var = (red[2] + red[3]) * (1.f / DV);
        float xn = core * rsqrtf(var + 1e-6f) * norm_w[t];
        float zv = ws[WS_Z + n * DV + t];
        float silz = zv / (1.f + expf(-zv));
        ws[WS_OUT + n * DV + t] = xn * silz;
    }
}

// ---- Kernel 3: output projection (wave per row, rows of length 4096) ----
__global__ void outproj_kernel(const float* __restrict__ ws,
                               const float* __restrict__ out_proj_w,
                               float* __restrict__ hidden_out) {
    int wave = (blockIdx.x * blockDim.x + threadIdx.x) >> 6;
    int lane = threadIdx.x & 63;
    if (wave >= H_DIM) return;
    const float4* row4 = (const float4*)(out_proj_w + (size_t)wave * VALUE_DIM);
    const float4* o4 = (const float4*)(ws + WS_OUT);
    float acc = 0.f;
#pragma unroll
    for (int i = 0; i < VALUE_DIM / 256; ++i) {  // 16 iters
        float4 w4 = row4[lane + 64 * i];
        float4 ov = o4[lane + 64 * i];
        acc += w4.x * ov.x + w4.y * ov.y + w4.z * ov.z + w4.w * ov.w;
    }
    acc = wave_reduce_sum(acc);
    if (lane == 0) hidden_out[wave] = acc;
}

extern "C" void kernel_launch(void* const* d_in, const int* in_sizes, int n_in,
                              void* d_out, int out_size, void* d_ws, size_t ws_size,
                              hipStream_t stream) {
    const float* h          = (const float*)d_in[0];   // (1,1,2048)
    const float* conv_state = (const float*)d_in[1];   // (1,8192,4)
    const float* rec_in     = (const float*)d_in[2];   // (1,32,128,128)
    const float* conv_w     = (const float*)d_in[3];   // (8192,4)
    const float* qkv_w      = (const float*)d_in[4];   // (8192,2048)
    const float* z_w        = (const float*)d_in[5];   // (4096,2048)
    const float* b_w        = (const float*)d_in[6];   // (32,2048)
    const float* a_w        = (const float*)d_in[7];   // (32,2048)
    const float* out_proj_w = (const float*)d_in[8];   // (2048,4096)
    const float* dt_bias    = (const float*)d_in[9];   // (32,)
    const float* A_log      = (const float*)d_in[10];  // (32,)
    const float* norm_w     = (const float*)d_in[11];  // (128,)

    float* out = (float*)d_out;
    float* hidden_out = out;                           // 2048
    float* new_conv   = out + H_DIM;                   // 32768
    float* rec_out    = out + H_DIM + CONV_DIM * KSZ;  // 524288
    float* ws = (float*)d_ws;

    // 1) projections: 12352 rows, 4 waves/block
    proj_kernel<<<3088, 256, 0, stream>>>(h, qkv_w, z_w, b_w, a_w, ws);
    // 2) fused conv + per-head state update
    head_kernel<<<32, 512, 0, stream>>>(conv_state, conv_w, ws, rec_in,
                                        dt_bias, A_log, norm_w, new_conv, rec_out);
    // 3) output projection
    outproj_kernel<<<512, 256, 0, stream>>>(ws, out_proj_w, hidden_out);
}